// Round 6
// baseline (345.072 us; speedup 1.0000x reference)
//
#include <hip/hip_runtime.h>

#define NTOK 196
#define NHEAD 12
#define HDIM 64
#define CDIM 768
#define BSZ 64
#define MROWS (BSZ * NTOK)          // 12544
#define PART_STRIDE 9633792         // 64*12*196*64
#define BH_STRIDE 12544             // 196*64
#define VT_LD 224                   // padded key dim for V^T rows (7 k-steps of 32)
#define VT_BH (HDIM * VT_LD)        // 14336
#define PM_H (NTOK * NTOK)          // 38416
#define P_LD 224                    // P strip row stride (16B-aligned rows)
#define K2_HALF 6272                // 196*32 (one kk half of K2)

typedef __bf16 bf16x8 __attribute__((ext_vector_type(8)));
typedef float f32x4 __attribute__((ext_vector_type(4)));

static __device__ __forceinline__ unsigned short f_to_bf16(float f) {
    union { float f; unsigned int i; } v; v.f = f;
    unsigned int x = v.i;
    unsigned int r = x + 0x7fffu + ((x >> 16) & 1u);  // RNE
    return (unsigned short)(r >> 16);
}

// async global->LDS, 16 B per lane. LDS dst must be wave-uniform base + lane*16.
static __device__ __forceinline__ void gld16(const unsigned short* g, unsigned short* l) {
    __builtin_amdgcn_global_load_lds(
        (__attribute__((address_space(1))) void*)(unsigned long long)(const void*)g,
        (__attribute__((address_space(3))) void*)(unsigned int)(unsigned long long)(void*)l,
        16, 0, 0);
}

// ---------------- fp32 -> bf16 cast (4 elems/thread) ----------------
__global__ void cvt_f32_bf16(const float* __restrict__ src,
                             unsigned short* __restrict__ dst, int n4) {
    int i = blockIdx.x * 256 + threadIdx.x;
    if (i >= n4) return;
    float4 v = ((const float4*)src)[i];
    ushort4 o;
    o.x = f_to_bf16(v.x); o.y = f_to_bf16(v.y);
    o.z = f_to_bf16(v.z); o.w = f_to_bf16(v.w);
    ((ushort4*)dst)[i] = o;
}

// ---- position map, query-major: pm2[h][i][j] = pos_map[i,j,h]*SCALE ----
__global__ void pos_kernel(const float* __restrict__ w1,   // (768,2)
                           const float* __restrict__ w1b,  // (768,)
                           const float* __restrict__ w2,   // (768,)
                           const float* __restrict__ b2,   // (12,)
                           float* __restrict__ pm2) {
    int idx = blockIdx.x * 256 + threadIdx.x;
    if (idx >= NHEAD * NTOK * NTOK) return;
    int h = idx / PM_H;
    int r = idx - h * PM_H;
    int i = r / NTOK;      // query row (slow)
    int j = r - i * NTOK;  // key col (fast)
    float rx = (float)(j % 14 - i % 14);   // indx[i][j]
    float ry = (float)(j / 14 - i / 14);   // indy[i][j]
    float acc = 0.f;
    int base = h * HDIM;
    #pragma unroll 8
    for (int t = 0; t < HDIM; ++t) {
        int c = base + t;
        float e = rx * w1[2 * c] + ry * w1[2 * c + 1] + w1b[c];
        e = e > 0.f ? e : 0.f;
        acc += e * w2[c];
    }
    pm2[idx] = (acc + b2[h]) * 0.125f;   // fold SCALE
}

// ---------------- GEMM1: qkv = x_bf @ w_cat^T (128x128 tile, dbuf K-loop)
// MODE 0 (cols 0..1535): swapped mfma(B,A) -> regs span d.
//   Q (part 0): dwordx2 to [b][h][n][64].
//   K (part 1): dwordx2 to K2 layout [b][h][kk][j][32] (kk = d>>5) for
//               conflict-free LDS staging in attention.
// MODE 1 (v, cols 1536..2303): normal mfma(A,B) -> regs span n -> dwordx2 to [b][h][d][VT_LD]
template <int MODE>
__global__ __launch_bounds__(256) void gemm_qkv_t(
        const unsigned short* __restrict__ A,   // [12544][768] bf16
        const unsigned short* __restrict__ W,   // [2304][768] bf16
        unsigned short* __restrict__ qkv,
        int n0base) {
    __shared__ __align__(16) unsigned short As[2][128 * 32];
    __shared__ __align__(16) unsigned short Bs[2][128 * 32];
    int tid = threadIdx.x;
    int m0 = blockIdx.y * 128;
    int n0 = n0base + blockIdx.x * 128;
    int w = tid >> 6, lane = tid & 63, l15 = lane & 15, quad = lane >> 4;
    int mw = (w & 1) * 64, nw = (w >> 1) * 64;

    const unsigned short* ga = A + (size_t)(m0 + (tid >> 2)) * CDIM + (tid & 3) * 8;
    const unsigned short* gb = W + (size_t)(n0 + (tid >> 2)) * CDIM + (tid & 3) * 8;

    f32x4 acc[4][4];
    #pragma unroll
    for (int i = 0; i < 4; ++i)
        #pragma unroll
        for (int j = 0; j < 4; ++j) acc[i][j] = (f32x4){0.f, 0.f, 0.f, 0.f};

    auto issue = [&](int buf) {
        gld16(ga, &As[buf][tid * 8]);
        gld16(ga + 64 * CDIM, &As[buf][2048 + tid * 8]);
        gld16(gb, &Bs[buf][tid * 8]);
        gld16(gb + 64 * CDIM, &Bs[buf][2048 + tid * 8]);
        ga += 32; gb += 32;
    };
    auto compute = [&](int buf) {
        bf16x8 af[4], bf[4];
        #pragma unroll
        for (int mt = 0; mt < 4; ++mt)
            af[mt] = *(const bf16x8*)&As[buf][(mw + mt * 16 + l15) * 32 + quad * 8];
        #pragma unroll
        for (int nt = 0; nt < 4; ++nt)
            bf[nt] = *(const bf16x8*)&Bs[buf][(nw + nt * 16 + l15) * 32 + quad * 8];
        #pragma unroll
        for (int mt = 0; mt < 4; ++mt)
            #pragma unroll
            for (int nt = 0; nt < 4; ++nt) {
                if (MODE == 0)
                    acc[mt][nt] = __builtin_amdgcn_mfma_f32_16x16x32_bf16(bf[nt], af[mt], acc[mt][nt], 0, 0, 0);
                else
                    acc[mt][nt] = __builtin_amdgcn_mfma_f32_16x16x32_bf16(af[mt], bf[nt], acc[mt][nt], 0, 0, 0);
            }
    };

    issue(0);  // stage 0
    #pragma unroll 1
    for (int kt = 0; kt < 24; kt += 2) {
        __syncthreads();           // vmcnt drain -> buf0 stage visible
        issue(1);                  // stage kt+1 (kt+1 <= 23 always)
        compute(0);
        __syncthreads();
        if (kt + 2 < 24) issue(0); // stage kt+2
        compute(1);
    }

    if (MODE == 0) {
        // regs span c (d within head); lanes span token m
        int part = (n0 >= CDIM) ? 1 : 0;
        const size_t pbase = (size_t)part * PART_STRIDE;
        int cb = n0 + nw + quad * 4 - part * CDIM;     // 0..767, mult of 4
        #pragma unroll
        for (int mt = 0; mt < 4; ++mt) {
            int m = m0 + mw + mt * 16 + l15;
            int b = m / NTOK, n = m - b * NTOK;
            #pragma unroll
            for (int nt = 0; nt < 4; ++nt) {
                int c = cb + nt * 16;
                int h = c >> 6, d = c & 63;
                uint2 pv;
                pv.x = (unsigned int)f_to_bf16(acc[mt][nt][0]) |
                       ((unsigned int)f_to_bf16(acc[mt][nt][1]) << 16);
                pv.y = (unsigned int)f_to_bf16(acc[mt][nt][2]) |
                       ((unsigned int)f_to_bf16(acc[mt][nt][3]) << 16);
                size_t idx;
                if (part == 0)
                    idx = (size_t)(b * NHEAD + h) * BH_STRIDE + n * HDIM + d;
                else  // K2: [bh][kk][j][32]
                    idx = pbase + (size_t)(b * NHEAD + h) * BH_STRIDE +
                          (d >> 5) * K2_HALF + n * 32 + (d & 31);
                *(uint2*)(qkv + idx) = pv;
            }
        }
    } else {
        // regs span token n (VT n-contiguous); lanes span c (d within head)
        #pragma unroll
        for (int mt = 0; mt < 4; ++mt) {
            int m = m0 + mw + mt * 16 + quad * 4;      // mult of 4; 4|196 so b,n uniform over r
            int b = m / NTOK, n = m - b * NTOK;
            size_t base_m = (size_t)2 * PART_STRIDE + (size_t)b * NHEAD * VT_BH + n;
            #pragma unroll
            for (int nt = 0; nt < 4; ++nt) {
                int c = n0 + nw + nt * 16 + l15 - 3 * 512;  // -1536
                int h = c >> 6, d = c & 63;
                uint2 pv;
                pv.x = (unsigned int)f_to_bf16(acc[mt][nt][0]) |
                       ((unsigned int)f_to_bf16(acc[mt][nt][1]) << 16);
                pv.y = (unsigned int)f_to_bf16(acc[mt][nt][2]) |
                       ((unsigned int)f_to_bf16(acc[mt][nt][3]) << 16);
                *(uint2*)(qkv + base_m + (size_t)h * VT_BH + d * VT_LD) = pv;
            }
        }
    }
}

// ---------------- MFMA attention v3: 1 block = (b,h), 4 waves ------------
// Swapped orientation: S^T = mfma(K,Q) -> lanes span i, regs span j.
// pm loads become float4; K staged once to LDS (K2 layout, 2-way-only banks);
// P strips wave-private; O = mfma(V,P) -> regs span d -> packed 8B stores.
__global__ __launch_bounds__(256, 3) void attn_mfma(
        const unsigned short* __restrict__ qkv,
        const float* __restrict__ pm2,
        unsigned short* __restrict__ attn_out) {
    __shared__ __align__(16) unsigned short Ks[2 * K2_HALF];     // 25088 B
    __shared__ __align__(16) unsigned short Pb[4][16 * P_LD];    // 28672 B
    int bh = blockIdx.x;
    int b = bh / NHEAD, h = bh - b * NHEAD;
    int tid = threadIdx.x;
    int w = tid >> 6, lane = tid & 63;
    int l15 = lane & 15, quad = lane >> 4;

    const unsigned short* qbase = qkv + (size_t)bh * BH_STRIDE;
    const unsigned short* kbase = qkv + (size_t)PART_STRIDE + (size_t)bh * BH_STRIDE;
    const unsigned short* vbase = qkv + (size_t)2 * PART_STRIDE + (size_t)bh * VT_BH;
    const float* pmh = pm2 + (size_t)h * PM_H;

    // stage K2 (25088 B) to LDS: flat copy, 16 B/lane
    #pragma unroll
    for (int r = 0; r < 7; ++r) {
        int idx = r * 2048 + tid * 8;
        if (idx < 2 * K2_HALF) gld16(kbase + idx, &Ks[idx]);
    }
    unsigned short* P = &Pb[w][0];
    // zero P pad cols [208,224) once (cols 196..207 get masked zeros each tile)
    {
        int row = lane >> 2, c = 208 + (lane & 3) * 4;
        *(uint2*)&P[row * P_LD + c] = (uint2){0u, 0u};
    }
    __syncthreads();   // K staged

    #pragma unroll 1
    for (int t = w; t < 13; t += 4) {
        // Q fragment (B-slot: lane l15 = i)
        int qrow = t * 16 + l15; if (qrow > 195) qrow = 195;
        bf16x8 aq0 = *(const bf16x8*)(qbase + qrow * HDIM + quad * 8);
        bf16x8 aq1 = *(const bf16x8*)(qbase + qrow * HDIM + 32 + quad * 8);

        // S^T = mfma(K, Q): lanes span i, regs span j
        f32x4 s[13];
        #pragma unroll
        for (int nt = 0; nt < 13; ++nt) s[nt] = (f32x4){0.f, 0.f, 0.f, 0.f};
        #pragma unroll
        for (int nt = 0; nt < 13; ++nt) {
            int jc = nt * 16 + l15; if (jc > 195) jc = 195;
            bf16x8 k0 = *(const bf16x8*)&Ks[jc * 32 + quad * 8];
            bf16x8 k1 = *(const bf16x8*)&Ks[K2_HALF + jc * 32 + quad * 8];
            s[nt] = __builtin_amdgcn_mfma_f32_16x16x32_bf16(k0, aq0, s[nt], 0, 0, 0);
            s[nt] = __builtin_amdgcn_mfma_f32_16x16x32_bf16(k1, aq1, s[nt], 0, 0, 0);
        }

        // softmax (max-free; scores O(1)): pm as float4, P -> LDS packed
        float rsum = 0.f;
        const float* pmrow = pmh + qrow * NTOK;
        #pragma unroll
        for (int nt = 0; nt < 13; ++nt) {
            int jb = nt * 16 + quad * 4;
            int jbl = jb > 192 ? 192 : jb;        // clamp load (nt=12, quad>0)
            float4 pmv = *(const float4*)(pmrow + jbl);
            float p0 = __expf(s[nt][0] * pmv.x);
            float p1 = __expf(s[nt][1] * pmv.y);
            float p2 = __expf(s[nt][2] * pmv.z);
            float p3 = __expf(s[nt][3] * pmv.w);
            if (jb + 0 > 195) p0 = 0.f;
            if (jb + 1 > 195) p1 = 0.f;
            if (jb + 2 > 195) p2 = 0.f;
            if (jb + 3 > 195) p3 = 0.f;
            rsum += (p0 + p1) + (p2 + p3);
            uint2 pk;
            pk.x = (unsigned int)f_to_bf16(p0) | ((unsigned int)f_to_bf16(p1) << 16);
            pk.y = (unsigned int)f_to_bf16(p2) | ((unsigned int)f_to_bf16(p3) << 16);
            *(uint2*)&P[l15 * P_LD + jb] = pk;
        }
        rsum += __shfl_xor(rsum, 16);
        rsum += __shfl_xor(rsum, 32);
        float inv = 1.f / rsum;

        // O^T = mfma(V, P): lanes span i, regs span d (4 consec)
        f32x4 o[4];
        #pragma unroll
        for (int dt = 0; dt < 4; ++dt) o[dt] = (f32x4){0.f, 0.f, 0.f, 0.f};
        #pragma unroll
        for (int kk = 0; kk < 7; ++kk) {
            bf16x8 pf = *(const bf16x8*)&P[l15 * P_LD + kk * 32 + quad * 8];
            #pragma unroll
            for (int dt = 0; dt < 4; ++dt) {
                bf16x8 vv = *(const bf16x8*)(vbase + (dt * 16 + l15) * VT_LD + kk * 32 + quad * 8);
                o[dt] = __builtin_amdgcn_mfma_f32_16x16x32_bf16(vv, pf, o[dt], 0, 0, 0);
            }
        }

        // store: lane = query row i, regs = 4 consec d -> 4 x 8B stores
        int orow = t * 16 + l15;
        if (orow < 196) {
            unsigned short* dst = attn_out + ((size_t)(b * NTOK + orow)) * CDIM + h * HDIM + quad * 4;
            #pragma unroll
            for (int dt = 0; dt < 4; ++dt) {
                uint2 ov;
                ov.x = (unsigned int)f_to_bf16(o[dt][0] * inv) |
                       ((unsigned int)f_to_bf16(o[dt][1] * inv) << 16);
                ov.y = (unsigned int)f_to_bf16(o[dt][2] * inv) |
                       ((unsigned int)f_to_bf16(o[dt][3] * inv) << 16);
                *(uint2*)(dst + dt * 16) = ov;
            }
        }
    }
}

// ------ GEMM2: out = attn_o @ proj_w^T + proj_b (swapped orient, float4 out)
__global__ __launch_bounds__(256) void gemm_proj(
        const unsigned short* __restrict__ A,   // [12544][768] bf16
        const unsigned short* __restrict__ W,   // [768][768] bf16
        const float* __restrict__ bias,         // (768,)
        float* __restrict__ out) {
    __shared__ __align__(16) unsigned short As[2][128 * 32];
    __shared__ __align__(16) unsigned short Bs[2][128 * 32];
    int tid = threadIdx.x;
    int m0 = blockIdx.y * 128;
    int n0 = blockIdx.x * 128;
    int w = tid >> 6, lane = tid & 63, l15 = lane & 15, quad = lane >> 4;
    int mw = (w & 1) * 64, nw = (w >> 1) * 64;

    const unsigned short* ga = A + (size_t)(m0 + (tid >> 2)) * CDIM + (tid & 3) * 8;
    const unsigned short* gb = W + (size_t)(n0 + (tid >> 2)) * CDIM + (tid & 3) * 8;

    f32x4 acc[4][4];
    #pragma unroll
    for (int i = 0; i < 4; ++i)
        #pragma unroll
        for (int j = 0; j < 4; ++j) acc[i][j] = (f32x4){0.f, 0.f, 0.f, 0.f};

    auto issue = [&](int buf) {
        gld16(ga, &As[buf][tid * 8]);
        gld16(ga + 64 * CDIM, &As[buf][2048 + tid * 8]);
        gld16(gb, &Bs[buf][tid * 8]);
        gld16(gb + 64 * CDIM, &Bs[buf][2048 + tid * 8]);
        ga += 32; gb += 32;
    };
    auto compute = [&](int buf) {
        bf16x8 af[4], bf[4];
        #pragma unroll
        for (int mt = 0; mt < 4; ++mt)
            af[mt] = *(const bf16x8*)&As[buf][(mw + mt * 16 + l15) * 32 + quad * 8];
        #pragma unroll
        for (int nt = 0; nt < 4; ++nt)
            bf[nt] = *(const bf16x8*)&Bs[buf][(nw + nt * 16 + l15) * 32 + quad * 8];
        #pragma unroll
        for (int mt = 0; mt < 4; ++mt)
            #pragma unroll
            for (int nt = 0; nt < 4; ++nt)
                acc[mt][nt] = __builtin_amdgcn_mfma_f32_16x16x32_bf16(bf[nt], af[mt], acc[mt][nt], 0, 0, 0);
    };

    issue(0);
    #pragma unroll 1
    for (int kt = 0; kt < 24; kt += 2) {
        __syncthreads();
        issue(1);
        compute(0);
        __syncthreads();
        if (kt + 2 < 24) issue(0);
        compute(1);
    }

    // swapped: regs span out-col c (4 consec), lanes span out-row m
    #pragma unroll
    for (int nt = 0; nt < 4; ++nt) {
        int c = n0 + nw + nt * 16 + quad * 4;
        float4 bv = *(const float4*)(bias + c);
        #pragma unroll
        for (int mt = 0; mt < 4; ++mt) {
            int m = m0 + mw + mt * 16 + l15;
            float4 ov;
            ov.x = acc[mt][nt][0] + bv.x;
            ov.y = acc[mt][nt][1] + bv.y;
            ov.z = acc[mt][nt][2] + bv.z;
            ov.w = acc[mt][nt][3] + bv.w;
            *(float4*)(out + (size_t)m * CDIM + c) = ov;
        }
    }
}

extern "C" void kernel_launch(void* const* d_in, const int* in_sizes, int n_in,
                              void* d_out, int out_size, void* d_ws, size_t ws_size,
                              hipStream_t stream) {
    const float* x      = (const float*)d_in[0];
    const float* qk_w   = (const float*)d_in[1];
    const float* v_w    = (const float*)d_in[2];
    const float* w1_w   = (const float*)d_in[3];
    const float* w1_b   = (const float*)d_in[4];
    const float* w2     = (const float*)d_in[5];
    const float* b2     = (const float*)d_in[6];
    const float* proj_w = (const float*)d_in[7];
    const float* proj_b = (const float*)d_in[8];
    float* out = (float*)d_out;

    // workspace layout (bf16 = unsigned short)
    unsigned short* x_bf  = (unsigned short*)d_ws;            // 9,633,792 elems
    unsigned short* w_cat = x_bf + 9633792;                   // 1,769,472
    unsigned short* pw_bf = w_cat + 1769472;                  //   589,824
    float* pm2            = (float*)(pw_bf + 589824);         //   460,992 f32
    unsigned short* qkv   = (unsigned short*)(pm2 + 460992);  // 30,277,632
    unsigned short* attn_o = x_bf;                            // alias (dead after gemm1)

    cvt_f32_bf16<<<9408, 256, 0, stream>>>(x, x_bf, 2408448);
    cvt_f32_bf16<<<1152, 256, 0, stream>>>(qk_w, w_cat, 294912);
    cvt_f32_bf16<<<576, 256, 0, stream>>>(v_w, w_cat + 1179648, 147456);
    cvt_f32_bf16<<<576, 256, 0, stream>>>(proj_w, pw_bf, 147456);
    pos_kernel<<<1801, 256, 0, stream>>>(w1_w, w1_b, w2, b2, pm2);

    dim3 gqk(12, 98);
    gemm_qkv_t<0><<<gqk, 256, 0, stream>>>(x_bf, w_cat, qkv, 0);
    dim3 gv(6, 98);
    gemm_qkv_t<1><<<gv, 256, 0, stream>>>(x_bf, w_cat, qkv, 1536);

    attn_mfma<<<768, 256, 0, stream>>>(qkv, pm2, attn_o);

    dim3 g2(6, 98);
    gemm_proj<<<g2, 256, 0, stream>>>(attn_o, pw_bf, proj_b, out);
}

// Round 7
// 314.810 us; speedup vs baseline: 1.0961x; 1.0961x over previous
//
#include <hip/hip_runtime.h>

#define NTOK 196
#define NHEAD 12
#define HDIM 64
#define CDIM 768
#define BSZ 64
#define MROWS (BSZ * NTOK)          // 12544
#define PART_STRIDE 9633792         // 64*12*196*64
#define BH_STRIDE 12544             // 196*64
#define VT_LD 224                   // padded key dim for V^T rows (7 k-steps of 32)
#define VT_BH (HDIM * VT_LD)        // 14336
#define PM_H (NTOK * NTOK)          // 38416
#define P_LD 232                    // P strip row stride (464 B: bank stride 20 -> 2-way = free)
#define K2G 6272                    // 196*32: one kk half of K2 in GLOBAL
#define K2L 7840                    // 196*40: one kk half of K2 in LDS (80 B rows)

typedef __bf16 bf16x8 __attribute__((ext_vector_type(8)));
typedef float f32x4 __attribute__((ext_vector_type(4)));

static __device__ __forceinline__ unsigned short f_to_bf16(float f) {
    union { float f; unsigned int i; } v; v.f = f;
    unsigned int x = v.i;
    unsigned int r = x + 0x7fffu + ((x >> 16) & 1u);  // RNE
    return (unsigned short)(r >> 16);
}

// async global->LDS, 16 B per lane. LDS dst must be wave-uniform base + lane*16.
static __device__ __forceinline__ void gld16(const unsigned short* g, unsigned short* l) {
    __builtin_amdgcn_global_load_lds(
        (__attribute__((address_space(1))) void*)(unsigned long long)(const void*)g,
        (__attribute__((address_space(3))) void*)(unsigned int)(unsigned long long)(void*)l,
        16, 0, 0);
}

// ---------------- fp32 -> bf16 cast (4 elems/thread) ----------------
__global__ void cvt_f32_bf16(const float* __restrict__ src,
                             unsigned short* __restrict__ dst, int n4) {
    int i = blockIdx.x * 256 + threadIdx.x;
    if (i >= n4) return;
    float4 v = ((const float4*)src)[i];
    ushort4 o;
    o.x = f_to_bf16(v.x); o.y = f_to_bf16(v.y);
    o.z = f_to_bf16(v.z); o.w = f_to_bf16(v.w);
    ((ushort4*)dst)[i] = o;
}

// ---- position map, query-major: pm2[h][i][j] = pos_map[i,j,h]*SCALE ----
__global__ void pos_kernel(const float* __restrict__ w1,   // (768,2)
                           const float* __restrict__ w1b,  // (768,)
                           const float* __restrict__ w2,   // (768,)
                           const float* __restrict__ b2,   // (12,)
                           float* __restrict__ pm2) {
    int idx = blockIdx.x * 256 + threadIdx.x;
    if (idx >= NHEAD * NTOK * NTOK) return;
    int h = idx / PM_H;
    int r = idx - h * PM_H;
    int i = r / NTOK;      // query row (slow)
    int j = r - i * NTOK;  // key col (fast)
    float rx = (float)(j % 14 - i % 14);   // indx[i][j]
    float ry = (float)(j / 14 - i / 14);   // indy[i][j]
    float acc = 0.f;
    int base = h * HDIM;
    #pragma unroll 8
    for (int t = 0; t < HDIM; ++t) {
        int c = base + t;
        float e = rx * w1[2 * c] + ry * w1[2 * c + 1] + w1b[c];
        e = e > 0.f ? e : 0.f;
        acc += e * w2[c];
    }
    pm2[idx] = (acc + b2[h]) * 0.125f;   // fold SCALE
}

// ---------------- GEMM1: qkv = x_bf @ w_cat^T (128x128 tile, dbuf K-loop)
// MODE 0 (cols 0..1535): swapped mfma(B,A) -> regs span d.
//   Q (part 0): dwordx2 to [b][h][n][64].
//   K (part 1): dwordx2 to K2 layout [b][h][kk][j][32] (kk = d>>5).
// MODE 1 (v, cols 1536..2303): normal mfma(A,B) -> regs span n -> dwordx2 to [b][h][d][VT_LD]
template <int MODE>
__global__ __launch_bounds__(256) void gemm_qkv_t(
        const unsigned short* __restrict__ A,   // [12544][768] bf16
        const unsigned short* __restrict__ W,   // [2304][768] bf16
        unsigned short* __restrict__ qkv,
        int n0base) {
    __shared__ __align__(16) unsigned short As[2][128 * 32];
    __shared__ __align__(16) unsigned short Bs[2][128 * 32];
    int tid = threadIdx.x;
    int m0 = blockIdx.y * 128;
    int n0 = n0base + blockIdx.x * 128;
    int w = tid >> 6, lane = tid & 63, l15 = lane & 15, quad = lane >> 4;
    int mw = (w & 1) * 64, nw = (w >> 1) * 64;

    const unsigned short* ga = A + (size_t)(m0 + (tid >> 2)) * CDIM + (tid & 3) * 8;
    const unsigned short* gb = W + (size_t)(n0 + (tid >> 2)) * CDIM + (tid & 3) * 8;

    f32x4 acc[4][4];
    #pragma unroll
    for (int i = 0; i < 4; ++i)
        #pragma unroll
        for (int j = 0; j < 4; ++j) acc[i][j] = (f32x4){0.f, 0.f, 0.f, 0.f};

    auto issue = [&](int buf) {
        gld16(ga, &As[buf][tid * 8]);
        gld16(ga + 64 * CDIM, &As[buf][2048 + tid * 8]);
        gld16(gb, &Bs[buf][tid * 8]);
        gld16(gb + 64 * CDIM, &Bs[buf][2048 + tid * 8]);
        ga += 32; gb += 32;
    };
    auto compute = [&](int buf) {
        bf16x8 af[4], bf[4];
        #pragma unroll
        for (int mt = 0; mt < 4; ++mt)
            af[mt] = *(const bf16x8*)&As[buf][(mw + mt * 16 + l15) * 32 + quad * 8];
        #pragma unroll
        for (int nt = 0; nt < 4; ++nt)
            bf[nt] = *(const bf16x8*)&Bs[buf][(nw + nt * 16 + l15) * 32 + quad * 8];
        #pragma unroll
        for (int mt = 0; mt < 4; ++mt)
            #pragma unroll
            for (int nt = 0; nt < 4; ++nt) {
                if (MODE == 0)
                    acc[mt][nt] = __builtin_amdgcn_mfma_f32_16x16x32_bf16(bf[nt], af[mt], acc[mt][nt], 0, 0, 0);
                else
                    acc[mt][nt] = __builtin_amdgcn_mfma_f32_16x16x32_bf16(af[mt], bf[nt], acc[mt][nt], 0, 0, 0);
            }
    };

    issue(0);  // stage 0
    #pragma unroll 1
    for (int kt = 0; kt < 24; kt += 2) {
        __syncthreads();           // vmcnt drain -> buf0 stage visible
        issue(1);                  // stage kt+1 (kt+1 <= 23 always)
        compute(0);
        __syncthreads();
        if (kt + 2 < 24) issue(0); // stage kt+2
        compute(1);
    }

    if (MODE == 0) {
        // regs span c (d within head); lanes span token m
        int part = (n0 >= CDIM) ? 1 : 0;
        const size_t pbase = (size_t)part * PART_STRIDE;
        int cb = n0 + nw + quad * 4 - part * CDIM;     // 0..767, mult of 4
        #pragma unroll
        for (int mt = 0; mt < 4; ++mt) {
            int m = m0 + mw + mt * 16 + l15;
            int b = m / NTOK, n = m - b * NTOK;
            #pragma unroll
            for (int nt = 0; nt < 4; ++nt) {
                int c = cb + nt * 16;
                int h = c >> 6, d = c & 63;
                uint2 pv;
                pv.x = (unsigned int)f_to_bf16(acc[mt][nt][0]) |
                       ((unsigned int)f_to_bf16(acc[mt][nt][1]) << 16);
                pv.y = (unsigned int)f_to_bf16(acc[mt][nt][2]) |
                       ((unsigned int)f_to_bf16(acc[mt][nt][3]) << 16);
                size_t idx;
                if (part == 0)
                    idx = (size_t)(b * NHEAD + h) * BH_STRIDE + n * HDIM + d;
                else  // K2: [bh][kk][j][32]
                    idx = pbase + (size_t)(b * NHEAD + h) * BH_STRIDE +
                          (d >> 5) * K2G + n * 32 + (d & 31);
                *(uint2*)(qkv + idx) = pv;
            }
        }
    } else {
        // regs span token n (VT n-contiguous); lanes span c (d within head)
        #pragma unroll
        for (int mt = 0; mt < 4; ++mt) {
            int m = m0 + mw + mt * 16 + quad * 4;      // mult of 4; 4|196 so b,n uniform over r
            int b = m / NTOK, n = m - b * NTOK;
            size_t base_m = (size_t)2 * PART_STRIDE + (size_t)b * NHEAD * VT_BH + n;
            #pragma unroll
            for (int nt = 0; nt < 4; ++nt) {
                int c = n0 + nw + nt * 16 + l15 - 3 * 512;  // -1536
                int h = c >> 6, d = c & 63;
                uint2 pv;
                pv.x = (unsigned int)f_to_bf16(acc[mt][nt][0]) |
                       ((unsigned int)f_to_bf16(acc[mt][nt][1]) << 16);
                pv.y = (unsigned int)f_to_bf16(acc[mt][nt][2]) |
                       ((unsigned int)f_to_bf16(acc[mt][nt][3]) << 16);
                *(uint2*)(qkv + base_m + (size_t)h * VT_BH + d * VT_LD) = pv;
            }
        }
    }
}

// ---------------- MFMA attention v4: 1 block = (b,h), 4 waves ------------
// S^T = mfma(K,Q): lanes span i -> pm float4 loads, 2-shuffle row sums.
// K repacked to LDS rows of 40 ushorts (16B-aligned b128, 2-way banks only).
// O = mfma(P, V^T): P already in A-layout in LDS; lanes span d -> coalesced
// 2B-contiguous stores (the 18.8 MB pattern). inv via 4 lane shuffles.
__global__ __launch_bounds__(256, 2) void attn_mfma(
        const unsigned short* __restrict__ qkv,
        const float* __restrict__ pm2,
        unsigned short* __restrict__ attn_out) {
    __shared__ __align__(16) unsigned short Ks[2 * K2L];         // 31360 B
    __shared__ __align__(16) unsigned short Pb[4][16 * P_LD];    // 29696 B
    int bh = blockIdx.x;
    int b = bh / NHEAD, h = bh - b * NHEAD;
    int tid = threadIdx.x;
    int w = tid >> 6, lane = tid & 63;
    int l15 = lane & 15, quad = lane >> 4;

    const unsigned short* qbase = qkv + (size_t)bh * BH_STRIDE;
    const unsigned short* kbase = qkv + (size_t)PART_STRIDE + (size_t)bh * BH_STRIDE;
    const unsigned short* vbase = qkv + (size_t)2 * PART_STRIDE + (size_t)bh * VT_BH;
    const float* pmh = pm2 + (size_t)h * PM_H;

    // repack K2 global [kk][j][32] -> LDS [kk][j][40]
    #pragma unroll
    for (int r = 0; r < 7; ++r) {
        int g = r * 2048 + tid * 8;
        if (g < 2 * K2G) {
            uint4 val = *(const uint4*)(kbase + g);
            int kk = (g >= K2G) ? 1 : 0;
            int rem = g - kk * K2G;
            int j = rem >> 5, c = rem & 31;
            *(uint4*)&Ks[kk * K2L + j * 40 + c] = val;
        }
    }
    unsigned short* P = &Pb[w][0];
    // zero P pad cols [208,224) once (cols 196..207 get masked zeros each tile)
    {
        int row = lane >> 2, c = 208 + (lane & 3) * 4;
        *(uint2*)&P[row * P_LD + c] = (uint2){0u, 0u};
    }
    __syncthreads();   // K staged

    #pragma unroll 1
    for (int t = w; t < 13; t += 4) {
        // Q fragment (B-slot: lane l15 = i)
        int qrow = t * 16 + l15; if (qrow > 195) qrow = 195;
        bf16x8 aq0 = *(const bf16x8*)(qbase + qrow * HDIM + quad * 8);
        bf16x8 aq1 = *(const bf16x8*)(qbase + qrow * HDIM + 32 + quad * 8);

        // S^T = mfma(K, Q): lanes span i, regs span j
        f32x4 s[13];
        #pragma unroll
        for (int nt = 0; nt < 13; ++nt) s[nt] = (f32x4){0.f, 0.f, 0.f, 0.f};
        #pragma unroll
        for (int nt = 0; nt < 13; ++nt) {
            int jc = nt * 16 + l15; if (jc > 195) jc = 195;
            bf16x8 k0 = *(const bf16x8*)&Ks[jc * 40 + quad * 8];
            bf16x8 k1 = *(const bf16x8*)&Ks[K2L + jc * 40 + quad * 8];
            s[nt] = __builtin_amdgcn_mfma_f32_16x16x32_bf16(k0, aq0, s[nt], 0, 0, 0);
            s[nt] = __builtin_amdgcn_mfma_f32_16x16x32_bf16(k1, aq1, s[nt], 0, 0, 0);
        }

        // softmax (max-free; scores O(1)): pm as float4, P -> LDS packed
        float rsum = 0.f;
        const float* pmrow = pmh + qrow * NTOK;
        #pragma unroll
        for (int nt = 0; nt < 13; ++nt) {
            int jb = nt * 16 + quad * 4;
            int jbl = jb > 192 ? 192 : jb;        // clamp load (nt=12, quad>0)
            float4 pmv = *(const float4*)(pmrow + jbl);
            float p0 = __expf(s[nt][0] * pmv.x);
            float p1 = __expf(s[nt][1] * pmv.y);
            float p2 = __expf(s[nt][2] * pmv.z);
            float p3 = __expf(s[nt][3] * pmv.w);
            if (jb + 0 > 195) p0 = 0.f;
            if (jb + 1 > 195) p1 = 0.f;
            if (jb + 2 > 195) p2 = 0.f;
            if (jb + 3 > 195) p3 = 0.f;
            rsum += (p0 + p1) + (p2 + p3);
            uint2 pk;
            pk.x = (unsigned int)f_to_bf16(p0) | ((unsigned int)f_to_bf16(p1) << 16);
            pk.y = (unsigned int)f_to_bf16(p2) | ((unsigned int)f_to_bf16(p3) << 16);
            *(uint2*)&P[l15 * P_LD + jb] = pk;
        }
        rsum += __shfl_xor(rsum, 16);
        rsum += __shfl_xor(rsum, 32);
        float inv = 1.f / rsum;   // lane (q, l15) holds inv for row i = t*16+l15

        // O = mfma(P, V^T): A = P rows (lane l15 = i), B = V^T rows (lane l15 = d)
        // C/D: col = l15 = d, row = quad*4+r = i -> coalesced 2B stores
        f32x4 o[4];
        #pragma unroll
        for (int dt = 0; dt < 4; ++dt) o[dt] = (f32x4){0.f, 0.f, 0.f, 0.f};
        #pragma unroll
        for (int kk = 0; kk < 7; ++kk) {
            bf16x8 pf = *(const bf16x8*)&P[l15 * P_LD + kk * 32 + quad * 8];
            #pragma unroll
            for (int dt = 0; dt < 4; ++dt) {
                bf16x8 vv = *(const bf16x8*)(vbase + (dt * 16 + l15) * VT_LD + kk * 32 + quad * 8);
                o[dt] = __builtin_amdgcn_mfma_f32_16x16x32_bf16(pf, vv, o[dt], 0, 0, 0);
            }
        }

        // store: row i = t*16 + quad*4 + r, col d = dt*16 + l15
        #pragma unroll
        for (int r = 0; r < 4; ++r) {
            int row = t * 16 + quad * 4 + r;
            if (row < 196) {
                float iv = __shfl(inv, quad * 4 + r);   // from lane l15 = quad*4+r
                unsigned short* dst = attn_out + ((size_t)(b * NTOK + row)) * CDIM + h * HDIM + l15;
                #pragma unroll
                for (int dt = 0; dt < 4; ++dt)
                    dst[dt * 16] = f_to_bf16(o[dt][r] * iv);
            }
        }
    }
}

// ------ GEMM2: out = attn_o @ proj_w^T + proj_b (swapped orient, float4 out)
__global__ __launch_bounds__(256) void gemm_proj(
        const unsigned short* __restrict__ A,   // [12544][768] bf16
        const unsigned short* __restrict__ W,   // [768][768] bf16
        const float* __restrict__ bias,         // (768,)
        float* __restrict__ out) {
    __shared__ __align__(16) unsigned short As[2][128 * 32];
    __shared__ __align__(16) unsigned short Bs[2][128 * 32];
    int tid = threadIdx.x;
    int m0 = blockIdx.y * 128;
    int n0 = blockIdx.x * 128;
    int w = tid >> 6, lane = tid & 63, l15 = lane & 15, quad = lane >> 4;
    int mw = (w & 1) * 64, nw = (w >> 1) * 64;

    const unsigned short* ga = A + (size_t)(m0 + (tid >> 2)) * CDIM + (tid & 3) * 8;
    const unsigned short* gb = W + (size_t)(n0 + (tid >> 2)) * CDIM + (tid & 3) * 8;

    f32x4 acc[4][4];
    #pragma unroll
    for (int i = 0; i < 4; ++i)
        #pragma unroll
        for (int j = 0; j < 4; ++j) acc[i][j] = (f32x4){0.f, 0.f, 0.f, 0.f};

    auto issue = [&](int buf) {
        gld16(ga, &As[buf][tid * 8]);
        gld16(ga + 64 * CDIM, &As[buf][2048 + tid * 8]);
        gld16(gb, &Bs[buf][tid * 8]);
        gld16(gb + 64 * CDIM, &Bs[buf][2048 + tid * 8]);
        ga += 32; gb += 32;
    };
    auto compute = [&](int buf) {
        bf16x8 af[4], bf[4];
        #pragma unroll
        for (int mt = 0; mt < 4; ++mt)
            af[mt] = *(const bf16x8*)&As[buf][(mw + mt * 16 + l15) * 32 + quad * 8];
        #pragma unroll
        for (int nt = 0; nt < 4; ++nt)
            bf[nt] = *(const bf16x8*)&Bs[buf][(nw + nt * 16 + l15) * 32 + quad * 8];
        #pragma unroll
        for (int mt = 0; mt < 4; ++mt)
            #pragma unroll
            for (int nt = 0; nt < 4; ++nt)
                acc[mt][nt] = __builtin_amdgcn_mfma_f32_16x16x32_bf16(bf[nt], af[mt], acc[mt][nt], 0, 0, 0);
    };

    issue(0);
    #pragma unroll 1
    for (int kt = 0; kt < 24; kt += 2) {
        __syncthreads();
        issue(1);
        compute(0);
        __syncthreads();
        if (kt + 2 < 24) issue(0);
        compute(1);
    }

    // swapped: regs span out-col c (4 consec), lanes span out-row m
    #pragma unroll
    for (int nt = 0; nt < 4; ++nt) {
        int c = n0 + nw + nt * 16 + quad * 4;
        float4 bv = *(const float4*)(bias + c);
        #pragma unroll
        for (int mt = 0; mt < 4; ++mt) {
            int m = m0 + mw + mt * 16 + l15;
            float4 ov;
            ov.x = acc[mt][nt][0] + bv.x;
            ov.y = acc[mt][nt][1] + bv.y;
            ov.z = acc[mt][nt][2] + bv.z;
            ov.w = acc[mt][nt][3] + bv.w;
            *(float4*)(out + (size_t)m * CDIM + c) = ov;
        }
    }
}

extern "C" void kernel_launch(void* const* d_in, const int* in_sizes, int n_in,
                              void* d_out, int out_size, void* d_ws, size_t ws_size,
                              hipStream_t stream) {
    const float* x      = (const float*)d_in[0];
    const float* qk_w   = (const float*)d_in[1];
    const float* v_w    = (const float*)d_in[2];
    const float* w1_w   = (const float*)d_in[3];
    const float* w1_b   = (const float*)d_in[4];
    const float* w2     = (const float*)d_in[5];
    const float* b2     = (const float*)d_in[6];
    const float* proj_w = (const float*)d_in[7];
    const float* proj_b = (const float*)d_in[8];
    float* out = (float*)d_out;

    // workspace layout (bf16 = unsigned short)
    unsigned short* x_bf  = (unsigned short*)d_ws;            // 9,633,792 elems
    unsigned short* w_cat = x_bf + 9633792;                   // 1,769,472
    unsigned short* pw_bf = w_cat + 1769472;                  //   589,824
    float* pm2            = (float*)(pw_bf + 589824);         //   460,992 f32
    unsigned short* qkv   = (unsigned short*)(pm2 + 460992);  // 30,277,632
    unsigned short* attn_o = x_bf;                            // alias (dead after gemm1)

    cvt_f32_bf16<<<9408, 256, 0, stream>>>(x, x_bf, 2408448);
    cvt_f32_bf16<<<1152, 256, 0, stream>>>(qk_w, w_cat, 294912);
    cvt_f32_bf16<<<576, 256, 0, stream>>>(v_w, w_cat + 1179648, 147456);
    cvt_f32_bf16<<<576, 256, 0, stream>>>(proj_w, pw_bf, 147456);
    pos_kernel<<<1801, 256, 0, stream>>>(w1_w, w1_b, w2, b2, pm2);

    dim3 gqk(12, 98);
    gemm_qkv_t<0><<<gqk, 256, 0, stream>>>(x_bf, w_cat, qkv, 0);
    dim3 gv(6, 98);
    gemm_qkv_t<1><<<gv, 256, 0, stream>>>(x_bf, w_cat, qkv, 1536);

    attn_mfma<<<768, 256, 0, stream>>>(qkv, pm2, attn_o);

    dim3 g2(6, 98);
    gemm_proj<<<g2, 256, 0, stream>>>(attn_o, pw_bf, proj_b, out);
}